// Round 2
// baseline (1645.229 us; speedup 1.0000x reference)
//
#include <hip/hip_runtime.h>
#include <math.h>

#define NEG_SLOPE 0.2f
#define BN_EPS 1e-5f

template <int N> struct IC { static constexpr int v = N; };
template <bool B> struct BC { static constexpr bool v = B; };

typedef _Float16 half2v __attribute__((ext_vector_type(2)));

__device__ __forceinline__ half2v u2h(unsigned u) {
  union { unsigned u; half2v h; } c;
  c.u = u;
  return c.h;
}
__device__ __forceinline__ unsigned pkh(float lo, float hi) {
  union { half2v h; unsigned u; } c;
  c.h[0] = (_Float16)lo;
  c.h[1] = (_Float16)hi;
  return c.u;
}

#if defined(__has_builtin)
#if __has_builtin(__builtin_amdgcn_fdot2)
#define FDOT2(a, b, c) __builtin_amdgcn_fdot2((a), (b), (c), false)
#endif
#endif
#ifndef FDOT2
__device__ __forceinline__ float fdot2_sw(half2v a, half2v b, float c) {
  return c + (float)a[0] * (float)b[0] + (float)a[1] * (float)b[1];
}
#define FDOT2(a, b, c) fdot2_sw((a), (b), (c))
#endif

// ---------------------------------------------------------------------------
// VALU-only 64-lane sum: 4 DPP row-rotate adds + 2 cross-row shuffles.
// ---------------------------------------------------------------------------
__device__ __forceinline__ float wave_sum64(float v) {
  int x;
  x = __builtin_amdgcn_update_dpp(0, __float_as_int(v), 0x121, 0xF, 0xF, true);
  v += __int_as_float(x);  // row_ror:1
  x = __builtin_amdgcn_update_dpp(0, __float_as_int(v), 0x122, 0xF, 0xF, true);
  v += __int_as_float(x);  // row_ror:2
  x = __builtin_amdgcn_update_dpp(0, __float_as_int(v), 0x124, 0xF, 0xF, true);
  v += __int_as_float(x);  // row_ror:4
  x = __builtin_amdgcn_update_dpp(0, __float_as_int(v), 0x128, 0xF, 0xF, true);
  v += __int_as_float(x);  // row_ror:8
  v += __shfl_xor(v, 16, 64);
  v += __shfl_xor(v, 32, 64);
  return v;
}

// ---------------------------------------------------------------------------
// Tile staging: 64 rows x 64 f32 -> LDS, per-lane coalesced (16 VMEM + 16
// ds_write_b128 per block; 0.25 mem-instr/node vs 16 for broadcast loads).
// Source rows clamped to stay in-bounds; garbage rows never stored.
// ---------------------------------------------------------------------------
__device__ __forceinline__ void stage_tile64(const float* __restrict__ src,
                                             float* __restrict__ sx, int n0,
                                             int rows, int w, int lane) {
  int gmax = rows * 64 - 4;
#pragma unroll
  for (int i = 0; i < 4; i++) {
    int off = w * 1024 + i * 256 + lane * 4;
    int g = n0 * 64 + off;
    g = min(g, gmax);
    float4 v = *(const float4*)(src + g);
    *(float4*)(sx + off) = v;
  }
}

__device__ __forceinline__ float dot64(const float* __restrict__ row,
                                       const float4* __restrict__ W, float b) {
  float a = b;
#pragma unroll
  for (int q = 0; q < 16; q++) {
    float4 v = ((const float4*)row)[q];
    a += v.x * W[q].x + v.y * W[q].y + v.z * W[q].z + v.w * W[q].w;
  }
  return a;
}

__device__ __forceinline__ void dot64x2(const float* __restrict__ row,
                                        const float4* __restrict__ Wa,
                                        const float4* __restrict__ Wb,
                                        float& da, float& db) {
#pragma unroll
  for (int q = 0; q < 16; q++) {
    float4 v = ((const float4*)row)[q];
    da += v.x * Wa[q].x + v.y * Wa[q].y + v.z * Wa[q].z + v.w * Wa[q].w;
    db += v.x * Wb[q].x + v.y * Wb[q].y + v.z * Wb[q].z + v.w * Wb[q].w;
  }
}

// ---------------------------------------------------------------------------
// hist + graph-counts merged.
// ---------------------------------------------------------------------------
__global__ __launch_bounds__(256) void hist_kernel(
    const int* __restrict__ dst, const int* __restrict__ batch,
    int* __restrict__ deg, float* __restrict__ counts, int E_, int N_) {
  int i = blockIdx.x * 256 + threadIdx.x;
  if (i < E_) atomicAdd(&deg[dst[i]], 1);
  if (i < N_) atomicAdd(&counts[batch[i]], 1.0f);
}

// ---------------------------------------------------------------------------
// Multi-block scan: A) per-256-segment local prefix + totals, B) one block
// scans totals, C) add offsets -> row_ptr/cursor.
// ---------------------------------------------------------------------------
__global__ __launch_bounds__(256) void scanA_kernel(
    const int* __restrict__ deg, int* __restrict__ row_ptr,
    int* __restrict__ segTot, int N_, int nseg) {
  __shared__ int sb[256];
  int t = threadIdx.x;
  for (int s = blockIdx.x; s < nseg; s += gridDim.x) {
    int i = s * 256 + t;
    int v = (i < N_) ? deg[i] : 0;
    sb[t] = v;
    __syncthreads();
    for (int off = 1; off < 256; off <<= 1) {
      int a = (t >= off) ? sb[t - off] : 0;
      __syncthreads();
      sb[t] += a;
      __syncthreads();
    }
    int incl = sb[t];
    if (i < N_) row_ptr[i] = incl - v;
    if (t == 255) segTot[s] = incl;
    __syncthreads();
  }
}

__global__ __launch_bounds__(256) void scanB_kernel(int* __restrict__ segTot,
                                                    int nseg) {
  __shared__ int sb[256];
  __shared__ int baseSh;
  int t = threadIdx.x;
  if (t == 0) baseSh = 0;
  __syncthreads();
  for (int c0 = 0; c0 < nseg; c0 += 256) {
    int s = c0 + t;
    int v = (s < nseg) ? segTot[s] : 0;
    sb[t] = v;
    __syncthreads();
    for (int off = 1; off < 256; off <<= 1) {
      int a = (t >= off) ? sb[t - off] : 0;
      __syncthreads();
      sb[t] += a;
      __syncthreads();
    }
    int incl = sb[t];
    int base = baseSh;
    if (s < nseg) segTot[s] = base + incl - v;
    __syncthreads();
    if (t == 255) baseSh = base + incl;
    __syncthreads();
  }
}

__global__ __launch_bounds__(256) void scanC_kernel(
    int* __restrict__ row_ptr, const int* __restrict__ segTot,
    int* __restrict__ cursor, int N_, int E_) {
  int tid = blockIdx.x * 256 + threadIdx.x;
  int nt = gridDim.x * 256;
  for (int i = tid; i < N_; i += nt) {
    int rp = row_ptr[i] + segTot[i >> 8];
    row_ptr[i] = rp;
    cursor[i] = rp;
  }
  if (tid == 0) row_ptr[N_] = E_;
}

// ---------------------------------------------------------------------------
// Scatter: src into CSR slot + attr permuted & converted to fp16 (32B/edge).
// Fallback (no ws room): write eid only, gat reads fp32 edge_attr.
// ---------------------------------------------------------------------------
__global__ __launch_bounds__(256) void scatter_kernel(
    const int* __restrict__ src, const int* __restrict__ dst,
    const float4* __restrict__ edge_attr4, int* __restrict__ cursor,
    int* __restrict__ csr_src, int* __restrict__ csr_eid,
    unsigned* __restrict__ attr_u, int E_) {
  int e = blockIdx.x * 256 + threadIdx.x;
  if (e >= E_) return;
  int pos = atomicAdd(&cursor[dst[e]], 1);
  csr_src[pos] = src[e];
  if (attr_u) {
    float4 a0 = edge_attr4[e * 4 + 0];
    float4 a1 = edge_attr4[e * 4 + 1];
    float4 a2 = edge_attr4[e * 4 + 2];
    float4 a3 = edge_attr4[e * 4 + 3];
    uint4 u0, u1;
    u0.x = pkh(a0.x, a0.y);
    u0.y = pkh(a0.z, a0.w);
    u0.z = pkh(a1.x, a1.y);
    u0.w = pkh(a1.z, a1.w);
    u1.x = pkh(a2.x, a2.y);
    u1.y = pkh(a2.z, a2.w);
    u1.z = pkh(a3.x, a3.y);
    u1.w = pkh(a3.z, a3.w);
    uint4* d4 = (uint4*)(attr_u + (size_t)pos * 8);
    d4[0] = u0;
    d4[1] = u1;
  } else {
    csr_eid[pos] = e;
  }
}

// ---------------------------------------------------------------------------
// Fused emb + layer-0 xl/xr, tile-staged:
//   - block stages 64 x-rows into LDS (coalesced per-lane loads).
//   - Phase A: h = emb(x) from broadcast ds_reads, W in VGPR; h rows written
//     to a second LDS slab (lane o -> [n][o], conflict-free) + global.
//   - Phase B/C: xl / xr from the h slab (each wave touches only its own 16
//     rows -> no second barrier). Phased (one W at a time) keeps VGPR ~<100.
// ---------------------------------------------------------------------------
__global__ __launch_bounds__(256, 4) void emb_lin0_kernel(
    const float* __restrict__ x, const float* __restrict__ emb_W,
    const float* __restrict__ emb_b, const float* __restrict__ Wl0,
    const float* __restrict__ bl0, const float* __restrict__ Wr0,
    const float* __restrict__ br0, float* __restrict__ h,
    _Float16* __restrict__ xl, _Float16* __restrict__ xr, int rows) {
  __shared__ float sx[4096];
  __shared__ float sh[4096];
  int lane = threadIdx.x & 63;
  int w = threadIdx.x >> 6;
  int n0 = blockIdx.x * 64;

  stage_tile64(x, sx, n0, rows, w, lane);
  __syncthreads();

  {  // ---- Phase A: h = x @ emb_W.T + emb_b ----
    float4 W[16];
#pragma unroll
    for (int q = 0; q < 16; q++) W[q] = ((const float4*)(emb_W + lane * 64))[q];
    float b = emb_b[lane];
#pragma unroll 1
    for (int t0 = 0; t0 < 16; t0 += 4) {
      int r = w * 16 + t0;
      float a0 = dot64(sx + (r + 0) * 64, W, b);
      float a1 = dot64(sx + (r + 1) * 64, W, b);
      float a2 = dot64(sx + (r + 2) * 64, W, b);
      float a3 = dot64(sx + (r + 3) * 64, W, b);
      sh[(r + 0) * 64 + lane] = a0;
      sh[(r + 1) * 64 + lane] = a1;
      sh[(r + 2) * 64 + lane] = a2;
      sh[(r + 3) * 64 + lane] = a3;
      int n = n0 + r;
      if (n + 0 < rows) h[(size_t)(n + 0) * 64 + lane] = a0;
      if (n + 1 < rows) h[(size_t)(n + 1) * 64 + lane] = a1;
      if (n + 2 < rows) h[(size_t)(n + 2) * 64 + lane] = a2;
      if (n + 3 < rows) h[(size_t)(n + 3) * 64 + lane] = a3;
    }
  }
  // Each wave reads back only its own 16 rows -> same-wave lgkm ordering,
  // no barrier needed.

  {  // ---- Phase B: xl = h @ Wl0.T + bl0 ----
    float4 W[16];
#pragma unroll
    for (int q = 0; q < 16; q++) W[q] = ((const float4*)(Wl0 + lane * 64))[q];
    float b = bl0[lane];
#pragma unroll 1
    for (int t0 = 0; t0 < 16; t0 += 4) {
      int r = w * 16 + t0;
      float a0 = dot64(sh + (r + 0) * 64, W, b);
      float a1 = dot64(sh + (r + 1) * 64, W, b);
      float a2 = dot64(sh + (r + 2) * 64, W, b);
      float a3 = dot64(sh + (r + 3) * 64, W, b);
      int n = n0 + r;
      if (n + 0 < rows) xl[(size_t)(n + 0) * 64 + lane] = (_Float16)a0;
      if (n + 1 < rows) xl[(size_t)(n + 1) * 64 + lane] = (_Float16)a1;
      if (n + 2 < rows) xl[(size_t)(n + 2) * 64 + lane] = (_Float16)a2;
      if (n + 3 < rows) xl[(size_t)(n + 3) * 64 + lane] = (_Float16)a3;
    }
  }

  {  // ---- Phase C: xr = h @ Wr0.T + br0 ----
    float4 W[16];
#pragma unroll
    for (int q = 0; q < 16; q++) W[q] = ((const float4*)(Wr0 + lane * 64))[q];
    float b = br0[lane];
#pragma unroll 1
    for (int t0 = 0; t0 < 16; t0 += 4) {
      int r = w * 16 + t0;
      float a0 = dot64(sh + (r + 0) * 64, W, b);
      float a1 = dot64(sh + (r + 1) * 64, W, b);
      float a2 = dot64(sh + (r + 2) * 64, W, b);
      float a3 = dot64(sh + (r + 3) * 64, W, b);
      int n = n0 + r;
      if (n + 0 < rows) xr[(size_t)(n + 0) * 64 + lane] = (_Float16)a0;
      if (n + 1 < rows) xr[(size_t)(n + 1) * 64 + lane] = (_Float16)a1;
      if (n + 2 < rows) xr[(size_t)(n + 2) * 64 + lane] = (_Float16)a2;
      if (n + 3 < rows) xr[(size_t)(n + 3) * 64 + lane] = (_Float16)a3;
    }
  }
}

// ---------------------------------------------------------------------------
// xl/xr for layers 1,2: tile-staged h + two phased passes (Wl then Wr) from
// broadcast ds_reads.
// ---------------------------------------------------------------------------
__global__ __launch_bounds__(256, 4) void linx2_kernel(
    const float* __restrict__ in, const float* __restrict__ Wl,
    const float* __restrict__ bl, const float* __restrict__ Wr,
    const float* __restrict__ br, _Float16* __restrict__ xl,
    _Float16* __restrict__ xr, int rows) {
  __shared__ float sx[4096];
  int lane = threadIdx.x & 63;
  int w = threadIdx.x >> 6;
  int n0 = blockIdx.x * 64;

  stage_tile64(in, sx, n0, rows, w, lane);
  __syncthreads();

  {  // ---- xl ----
    float4 W[16];
#pragma unroll
    for (int q = 0; q < 16; q++) W[q] = ((const float4*)(Wl + lane * 64))[q];
    float b = bl[lane];
#pragma unroll 1
    for (int t0 = 0; t0 < 16; t0 += 4) {
      int r = w * 16 + t0;
      float a0 = dot64(sx + (r + 0) * 64, W, b);
      float a1 = dot64(sx + (r + 1) * 64, W, b);
      float a2 = dot64(sx + (r + 2) * 64, W, b);
      float a3 = dot64(sx + (r + 3) * 64, W, b);
      int n = n0 + r;
      if (n + 0 < rows) xl[(size_t)(n + 0) * 64 + lane] = (_Float16)a0;
      if (n + 1 < rows) xl[(size_t)(n + 1) * 64 + lane] = (_Float16)a1;
      if (n + 2 < rows) xl[(size_t)(n + 2) * 64 + lane] = (_Float16)a2;
      if (n + 3 < rows) xl[(size_t)(n + 3) * 64 + lane] = (_Float16)a3;
    }
  }

  {  // ---- xr ----
    float4 W[16];
#pragma unroll
    for (int q = 0; q < 16; q++) W[q] = ((const float4*)(Wr + lane * 64))[q];
    float b = br[lane];
#pragma unroll 1
    for (int t0 = 0; t0 < 16; t0 += 4) {
      int r = w * 16 + t0;
      float a0 = dot64(sx + (r + 0) * 64, W, b);
      float a1 = dot64(sx + (r + 1) * 64, W, b);
      float a2 = dot64(sx + (r + 2) * 64, W, b);
      float a3 = dot64(sx + (r + 3) * 64, W, b);
      int n = n0 + r;
      if (n + 0 < rows) xr[(size_t)(n + 0) * 64 + lane] = (_Float16)a0;
      if (n + 1 < rows) xr[(size_t)(n + 1) * 64 + lane] = (_Float16)a1;
      if (n + 2 < rows) xr[(size_t)(n + 2) * 64 + lane] = (_Float16)a2;
      if (n + 3 < rows) xr[(size_t)(n + 3) * 64 + lane] = (_Float16)a3;
    }
  }
}

// ---------------------------------------------------------------------------
// Fused GATv2 layer (round-8 proven structure): one wave per node; full-16 ->
// full-8 -> padded-8 chunks; wave-uniform scalar index/attr loads; 16
// independent fp16 xl gathers; ea via 8 v_dot2_f32_f16; DPP reduction;
// online-max softmax. Epilogue = folded conv_bias+BN, exact GELU, residual.
// ---------------------------------------------------------------------------
template <bool CONTIG>
__global__ __launch_bounds__(256) void gat_fused_kernel(
    const int* __restrict__ csr_src, const int* __restrict__ csr_eid,
    const int* __restrict__ row_ptr, const unsigned* __restrict__ attr_u,
    const float* __restrict__ edge_attr, const _Float16* __restrict__ xl,
    const _Float16* __restrict__ xr, const float* __restrict__ We,
    const float* __restrict__ att, const float* __restrict__ conv_bias,
    const float* __restrict__ gamma, const float* __restrict__ beta,
    const float* __restrict__ mean, const float* __restrict__ var,
    float* __restrict__ h, int N_) {
  int d = (blockIdx.x * 256 + threadIdx.x) >> 6;
  if (d >= N_) return;
  int j = threadIdx.x & 63;
  half2v Wek2[8];
  float Wekf[16];
  if constexpr (CONTIG) {
#pragma unroll
    for (int q = 0; q < 8; q++) {
      Wek2[q][0] = (_Float16)We[j * 16 + 2 * q];
      Wek2[q][1] = (_Float16)We[j * 16 + 2 * q + 1];
    }
  } else {
#pragma unroll
    for (int k = 0; k < 16; k++) Wekf[k] = We[j * 16 + k];
  }
  float att_j = att[j];
  float sc = rsqrtf(var[j] + BN_EPS) * gamma[j];
  float sh = (conv_bias[j] - mean[j]) * sc + beta[j];

  int beg = __builtin_amdgcn_readfirstlane(row_ptr[d]);
  int end = __builtin_amdgcn_readfirstlane(row_ptr[d + 1]);
  float xrj = (float)xr[(size_t)d * 64 + j];
  float m = -INFINITY, l = 0.f, acc = 0.f;

  auto chunk = [&](int base, auto C_, auto PAD_) {
    constexpr int C = decltype(C_)::v;
    constexpr bool PAD = decltype(PAD_)::v;
    int si[C];
#pragma unroll
    for (int t = 0; t < C; t++) {
      int idx = PAD ? min(base + t, end - 1) : (base + t);
      si[t] = csr_src[idx];
    }
    float xlv[C];
#pragma unroll
    for (int t = 0; t < C; t++)
      xlv[t] = (float)xl[(size_t)si[t] * 64 + j];
    float v[C];
#pragma unroll
    for (int t = 0; t < C; t++) {
      int idx = PAD ? min(base + t, end - 1) : (base + t);
      float ea;
      if constexpr (CONTIG) {
        const uint4* ap = (const uint4*)(attr_u + (size_t)idx * 8);
        uint4 ua = ap[0], ub = ap[1];  // uniform -> s_load_dwordx4
        ea = 0.f;
        ea = FDOT2(u2h(ua.x), Wek2[0], ea);
        ea = FDOT2(u2h(ua.y), Wek2[1], ea);
        ea = FDOT2(u2h(ua.z), Wek2[2], ea);
        ea = FDOT2(u2h(ua.w), Wek2[3], ea);
        ea = FDOT2(u2h(ub.x), Wek2[4], ea);
        ea = FDOT2(u2h(ub.y), Wek2[5], ea);
        ea = FDOT2(u2h(ub.z), Wek2[6], ea);
        ea = FDOT2(u2h(ub.w), Wek2[7], ea);
      } else {
        const float4* ap =
            (const float4*)(edge_attr + (size_t)csr_eid[idx] * 16);
        float4 a0 = ap[0], a1 = ap[1], a2 = ap[2], a3 = ap[3];
        ea = a0.x * Wekf[0]  + a0.y * Wekf[1]  + a0.z * Wekf[2]  + a0.w * Wekf[3]
           + a1.x * Wekf[4]  + a1.y * Wekf[5]  + a1.z * Wekf[6]  + a1.w * Wekf[7]
           + a2.x * Wekf[8]  + a2.y * Wekf[9]  + a2.z * Wekf[10] + a2.w * Wekf[11]
           + a3.x * Wekf[12] + a3.y * Wekf[13] + a3.z * Wekf[14] + a3.w * Wekf[15];
      }
      float z = xlv[t] + xrj + ea;
      z = fmaxf(z, NEG_SLOPE * z);  // leaky_relu
      float p = wave_sum64(z * att_j);
      v[t] = (!PAD || (base + t < end)) ? p : -INFINITY;
    }
    float mc = v[0];
#pragma unroll
    for (int t = 1; t < C; t++) mc = fmaxf(mc, v[t]);
    float newm = fmaxf(m, mc);
    float s = __expf(m - newm);  // first chunk: exp(-inf)=0
    l *= s;
    acc *= s;
#pragma unroll
    for (int t = 0; t < C; t++) {
      float w = __expf(v[t] - newm);  // padded slots: exp(-inf)=0
      l += w;
      acc += w * xlv[t];
    }
    m = newm;
  };

  int base = beg;
  for (; base + 16 <= end; base += 16) chunk(base, IC<16>{}, BC<false>{});
  if (base + 8 <= end) {
    chunk(base, IC<8>{}, BC<false>{});
    base += 8;
  }
  if (base < end) chunk(base, IC<8>{}, BC<true>{});

  float val = acc / (l + 1e-16f) * sc + sh;  // conv_bias+BN folded
  float g = 0.5f * val * (1.f + erff(val * 0.70710678118654752f));
  h[(size_t)d * 64 + j] += g;
}

// ---------------------------------------------------------------------------
// Final: out128 = h @ lin_W.T + lin_b, pooled per graph (batch sorted),
// mean fused at flush. Tile-staged h; wave w handles nodes w*16..w*16+15,
// lane holds outputs (lane, lane+64); one broadcast ds_read feeds both dots.
// ---------------------------------------------------------------------------
__global__ __launch_bounds__(256, 3) void lin_pool_kernel(
    const float* __restrict__ h, const float* __restrict__ lin_W,
    const float* __restrict__ lin_b, const int* __restrict__ batch,
    const float* __restrict__ counts, float* __restrict__ pooled, int rows) {
  __shared__ float shh[4096];
  int lane = threadIdx.x & 63;
  int w = threadIdx.x >> 6;
  int n0 = blockIdx.x * 64;

  stage_tile64(h, shh, n0, rows, w, lane);
  __syncthreads();

  float4 W0[16], W1[16];
#pragma unroll
  for (int q = 0; q < 16; q++) W0[q] = ((const float4*)(lin_W + lane * 64))[q];
#pragma unroll
  for (int q = 0; q < 16; q++)
    W1[q] = ((const float4*)(lin_W + (lane + 64) * 64))[q];
  float b0 = lin_b[lane], b1 = lin_b[lane + 64];

  int curg = -1;
  float acc0 = 0.f, acc1 = 0.f;
  int lim = min(16, rows - n0 - w * 16);
  for (int t = 0; t < lim; t++) {
    int r = w * 16 + t;
    float d0 = b0, d1 = b1;
    dot64x2(shh + r * 64, W0, W1, d0, d1);
    int g = batch[n0 + r];
    if (g != curg) {
      if (curg >= 0) {
        float inv = 1.f / fmaxf(counts[curg], 1.f);
        atomicAdd(&pooled[curg * 128 + lane], acc0 * inv);
        atomicAdd(&pooled[curg * 128 + 64 + lane], acc1 * inv);
      }
      curg = g;
      acc0 = 0.f;
      acc1 = 0.f;
    }
    acc0 += d0;
    acc1 += d1;
  }
  if (curg >= 0) {
    float inv = 1.f / fmaxf(counts[curg], 1.f);
    atomicAdd(&pooled[curg * 128 + lane], acc0 * inv);
    atomicAdd(&pooled[curg * 128 + 64 + lane], acc1 * inv);
  }
}

extern "C" void kernel_launch(void* const* d_in, const int* in_sizes, int n_in,
                              void* d_out, int out_size, void* d_ws, size_t ws_size,
                              hipStream_t stream) {
  const float* x         = (const float*)d_in[0];
  const int*   edge_index= (const int*)  d_in[1];
  const float* edge_attr = (const float*)d_in[2];
  const int*   batch     = (const int*)  d_in[3];
  const float* emb_W     = (const float*)d_in[4];
  const float* emb_b     = (const float*)d_in[5];
  const float* Wl        = (const float*)d_in[6];
  const float* bl        = (const float*)d_in[7];
  const float* Wr        = (const float*)d_in[8];
  const float* br        = (const float*)d_in[9];
  const float* We        = (const float*)d_in[10];
  const float* att       = (const float*)d_in[11];
  const float* conv_bias = (const float*)d_in[12];
  const float* bn_gamma  = (const float*)d_in[13];
  const float* bn_beta   = (const float*)d_in[14];
  const float* bn_mean   = (const float*)d_in[15];
  const float* bn_var    = (const float*)d_in[16];
  const float* lin_W     = (const float*)d_in[17];
  const float* lin_b     = (const float*)d_in[18];

  const int N_ = in_sizes[0] / 64;
  const int E_ = in_sizes[1] / 2;
  const int G_ = out_size / 128;
  const int* src = edge_index;
  const int* dst = edge_index + E_;

  const int Npad = (N_ + 3) & ~3;
  const int Epad = (E_ + 19) & ~3;
  const int nseg = (N_ + 255) / 256;

  // Workspace layout (floats). xl/xr are fp16 (N*32 float-slots each).
  float* ws      = (float*)d_ws;
  float* h       = ws;                                 // N*64
  _Float16* xl   = (_Float16*)(h + (size_t)N_ * 64);   // N*64 halfs
  _Float16* xr   = xl + (size_t)N_ * 64;               // N*64 halfs
  int*   csr_src = (int*)(xr + (size_t)N_ * 64);       // Epad
  int*   csr_eid = csr_src + Epad;                     // Epad
  int*   row_ptr = csr_eid + Epad;                     // Npad+4
  int*   cursor  = row_ptr + (Npad + 4);               // Npad
  int*   deg     = cursor + Npad;                      // Npad
  float* counts  = (float*)(deg + Npad);               // G
  int*   segTot  = (int*)(counts + G_);                // nseg+8
  uintptr_t abp  = (uintptr_t)(segTot + nseg + 8);
  abp = (abp + 15) & ~(uintptr_t)15;
  unsigned* attr_u = (unsigned*)abp;                   // E*8 uints (optional)

  size_t base_bytes = (abp - (uintptr_t)d_ws);
  bool contig = ws_size >= base_bytes + (size_t)E_ * 32 + 64;

  const int hgrid = (max(E_, N_) + 255) / 256;
  const int ngrid = (N_ + 255) / 256;

  // --- CSR build + graph counts (once per call, reused by all 3 layers) ---
  hipMemsetAsync(deg, 0, ((size_t)Npad + G_) * 4, stream);  // deg + counts
  hist_kernel<<<hgrid, 256, 0, stream>>>(dst, batch, deg, counts, E_, N_);
  scanA_kernel<<<min(nseg, 1024), 256, 0, stream>>>(deg, row_ptr, segTot, N_,
                                                    nseg);
  scanB_kernel<<<1, 256, 0, stream>>>(segTot, nseg);
  scanC_kernel<<<ngrid, 256, 0, stream>>>(row_ptr, segTot, cursor, N_, E_);
  scatter_kernel<<<(E_ + 255) / 256, 256, 0, stream>>>(
      src, dst, (const float4*)edge_attr, cursor, csr_src, csr_eid,
      contig ? attr_u : (unsigned*)nullptr, E_);

  // h = emb(x); xl/xr for layer 0 (tile-staged)
  const int tgrid = (N_ + 63) / 64;  // one 64-node tile per block
  emb_lin0_kernel<<<tgrid, 256, 0, stream>>>(x, emb_W, emb_b, Wl, bl, Wr, br,
                                             h, xl, xr, N_);

  const int gatBlocks = (N_ + 3) / 4;  // one wave per node
  for (int l = 0; l < 3; l++) {
    if (l > 0) {
      linx2_kernel<<<tgrid, 256, 0, stream>>>(
          h, Wl + (size_t)l * 4096, bl + l * 64, Wr + (size_t)l * 4096,
          br + l * 64, xl, xr, N_);
    }
    if (contig) {
      gat_fused_kernel<true><<<gatBlocks, 256, 0, stream>>>(
          csr_src, csr_eid, row_ptr, attr_u, edge_attr, xl, xr,
          We + (size_t)l * 1024, att + l * 64, conv_bias + l * 64,
          bn_gamma + l * 64, bn_beta + l * 64, bn_mean + l * 64,
          bn_var + l * 64, h, N_);
    } else {
      gat_fused_kernel<false><<<gatBlocks, 256, 0, stream>>>(
          csr_src, csr_eid, row_ptr, attr_u, edge_attr, xl, xr,
          We + (size_t)l * 1024, att + l * 64, conv_bias + l * 64,
          bn_gamma + l * 64, bn_beta + l * 64, bn_mean + l * 64,
          bn_var + l * 64, h, N_);
    }
  }

  hipMemsetAsync(d_out, 0, (size_t)G_ * 128 * 4, stream);
  lin_pool_kernel<<<(N_ + 63) / 64, 256, 0, stream>>>(
      h, lin_W, lin_b, batch, counts, (float*)d_out, N_);
}

// Round 3
// 1271.467 us; speedup vs baseline: 1.2940x; 1.2940x over previous
//
#include <hip/hip_runtime.h>
#include <math.h>

#define NEG_SLOPE 0.2f
#define BN_EPS 1e-5f

template <int N> struct IC { static constexpr int v = N; };
template <bool B> struct BC { static constexpr bool v = B; };

typedef _Float16 half2v __attribute__((ext_vector_type(2)));

__device__ __forceinline__ half2v u2h(unsigned u) {
  union { unsigned u; half2v h; } c;
  c.u = u;
  return c.h;
}
__device__ __forceinline__ unsigned pkh(float lo, float hi) {
  union { half2v h; unsigned u; } c;
  c.h[0] = (_Float16)lo;
  c.h[1] = (_Float16)hi;
  return c.u;
}

#if defined(__has_builtin)
#if __has_builtin(__builtin_amdgcn_fdot2)
#define FDOT2(a, b, c) __builtin_amdgcn_fdot2((a), (b), (c), false)
#endif
#endif
#ifndef FDOT2
__device__ __forceinline__ float fdot2_sw(half2v a, half2v b, float c) {
  return c + (float)a[0] * (float)b[0] + (float)a[1] * (float)b[1];
}
#define FDOT2(a, b, c) fdot2_sw((a), (b), (c))
#endif

// FMA of one float4 pair into scalar accumulator (expanded inline at use).
#define FMA4(acc, v, wq) \
  acc += (v).x * (wq).x + (v).y * (wq).y + (v).z * (wq).z + (v).w * (wq).w

// ---------------------------------------------------------------------------
// VALU-only 64-lane sum: 4 DPP row-rotate adds + 2 cross-row shuffles.
// ---------------------------------------------------------------------------
__device__ __forceinline__ float wave_sum64(float v) {
  int x;
  x = __builtin_amdgcn_update_dpp(0, __float_as_int(v), 0x121, 0xF, 0xF, true);
  v += __int_as_float(x);  // row_ror:1
  x = __builtin_amdgcn_update_dpp(0, __float_as_int(v), 0x122, 0xF, 0xF, true);
  v += __int_as_float(x);  // row_ror:2
  x = __builtin_amdgcn_update_dpp(0, __float_as_int(v), 0x124, 0xF, 0xF, true);
  v += __int_as_float(x);  // row_ror:4
  x = __builtin_amdgcn_update_dpp(0, __float_as_int(v), 0x128, 0xF, 0xF, true);
  v += __int_as_float(x);  // row_ror:8
  v += __shfl_xor(v, 16, 64);
  v += __shfl_xor(v, 32, 64);
  return v;
}

// ---------------------------------------------------------------------------
// hist + graph-counts merged.
// ---------------------------------------------------------------------------
__global__ __launch_bounds__(256) void hist_kernel(
    const int* __restrict__ dst, const int* __restrict__ batch,
    int* __restrict__ deg, float* __restrict__ counts, int E_, int N_) {
  int i = blockIdx.x * 256 + threadIdx.x;
  if (i < E_) atomicAdd(&deg[dst[i]], 1);
  if (i < N_) atomicAdd(&counts[batch[i]], 1.0f);
}

// ---------------------------------------------------------------------------
// Multi-block scan: A) per-256-segment local prefix + totals, B) one block
// scans totals, C) add offsets -> row_ptr/cursor.
// ---------------------------------------------------------------------------
__global__ __launch_bounds__(256) void scanA_kernel(
    const int* __restrict__ deg, int* __restrict__ row_ptr,
    int* __restrict__ segTot, int N_, int nseg) {
  __shared__ int sb[256];
  int t = threadIdx.x;
  for (int s = blockIdx.x; s < nseg; s += gridDim.x) {
    int i = s * 256 + t;
    int v = (i < N_) ? deg[i] : 0;
    sb[t] = v;
    __syncthreads();
    for (int off = 1; off < 256; off <<= 1) {
      int a = (t >= off) ? sb[t - off] : 0;
      __syncthreads();
      sb[t] += a;
      __syncthreads();
    }
    int incl = sb[t];
    if (i < N_) row_ptr[i] = incl - v;
    if (t == 255) segTot[s] = incl;
    __syncthreads();
  }
}

__global__ __launch_bounds__(256) void scanB_kernel(int* __restrict__ segTot,
                                                    int nseg) {
  __shared__ int sb[256];
  __shared__ int baseSh;
  int t = threadIdx.x;
  if (t == 0) baseSh = 0;
  __syncthreads();
  for (int c0 = 0; c0 < nseg; c0 += 256) {
    int s = c0 + t;
    int v = (s < nseg) ? segTot[s] : 0;
    sb[t] = v;
    __syncthreads();
    for (int off = 1; off < 256; off <<= 1) {
      int a = (t >= off) ? sb[t - off] : 0;
      __syncthreads();
      sb[t] += a;
      __syncthreads();
    }
    int incl = sb[t];
    int base = baseSh;
    if (s < nseg) segTot[s] = base + incl - v;
    __syncthreads();
    if (t == 255) baseSh = base + incl;
    __syncthreads();
  }
}

__global__ __launch_bounds__(256) void scanC_kernel(
    int* __restrict__ row_ptr, const int* __restrict__ segTot,
    int* __restrict__ cursor, int N_, int E_) {
  int tid = blockIdx.x * 256 + threadIdx.x;
  int nt = gridDim.x * 256;
  for (int i = tid; i < N_; i += nt) {
    int rp = row_ptr[i] + segTot[i >> 8];
    row_ptr[i] = rp;
    cursor[i] = rp;
  }
  if (tid == 0) row_ptr[N_] = E_;
}

// ---------------------------------------------------------------------------
// Scatter: src into CSR slot + attr permuted & converted to fp16 (32B/edge).
// Fallback (no ws room): write eid only, gat reads fp32 edge_attr.
// ---------------------------------------------------------------------------
__global__ __launch_bounds__(256) void scatter_kernel(
    const int* __restrict__ src, const int* __restrict__ dst,
    const float4* __restrict__ edge_attr4, int* __restrict__ cursor,
    int* __restrict__ csr_src, int* __restrict__ csr_eid,
    unsigned* __restrict__ attr_u, int E_) {
  int e = blockIdx.x * 256 + threadIdx.x;
  if (e >= E_) return;
  int pos = atomicAdd(&cursor[dst[e]], 1);
  csr_src[pos] = src[e];
  if (attr_u) {
    float4 a0 = edge_attr4[e * 4 + 0];
    float4 a1 = edge_attr4[e * 4 + 1];
    float4 a2 = edge_attr4[e * 4 + 2];
    float4 a3 = edge_attr4[e * 4 + 3];
    uint4 u0, u1;
    u0.x = pkh(a0.x, a0.y);
    u0.y = pkh(a0.z, a0.w);
    u0.z = pkh(a1.x, a1.y);
    u0.w = pkh(a1.z, a1.w);
    u1.x = pkh(a2.x, a2.y);
    u1.y = pkh(a2.z, a2.w);
    u1.z = pkh(a3.x, a3.y);
    u1.w = pkh(a3.z, a3.w);
    uint4* d4 = (uint4*)(attr_u + (size_t)pos * 8);
    d4[0] = u0;
    d4[1] = u1;
  } else {
    csr_eid[pos] = e;
  }
}

// ---------------------------------------------------------------------------
// Fused emb + layer-0 xl/xr, tile-staged, ALL dot products hand-inlined
// (no register array ever passed by pointer -> no scratch spills):
//   - block stages 64 x-rows into LDS with per-lane coalesced float4 loads.
//   - Phase A: h = emb(x); broadcast ds_read_b128 of the row, W in VGPRs.
//     h rows -> second LDS slab + global.
//   - Phase B/C: xl / xr from the h slab. Each wave only touches its own 16
//     rows -> same-wave lgkm ordering, no second barrier. Phased (one W at a
//     time) keeps VGPR ~110.
// ---------------------------------------------------------------------------
__global__ __launch_bounds__(256, 3) void emb_lin0_kernel(
    const float* __restrict__ x, const float* __restrict__ emb_W,
    const float* __restrict__ emb_b, const float* __restrict__ Wl0,
    const float* __restrict__ bl0, const float* __restrict__ Wr0,
    const float* __restrict__ br0, float* __restrict__ h,
    _Float16* __restrict__ xl, _Float16* __restrict__ xr, int rows) {
  __shared__ float sx[4096];
  __shared__ float sh[4096];
  int lane = threadIdx.x & 63;
  int w = threadIdx.x >> 6;
  int n0 = blockIdx.x * 64;

  {  // stage x tile: 16 coalesced float4 loads per wave
    int gmax = rows * 64 - 4;
#pragma unroll
    for (int i = 0; i < 4; i++) {
      int off = w * 1024 + i * 256 + lane * 4;
      int g = min(n0 * 64 + off, gmax);
      *(float4*)(sx + off) = *(const float4*)(x + g);
    }
  }
  __syncthreads();

  float4 W[16];
  float b;

  // ---- Phase A: h = x @ emb_W.T + emb_b ----
#pragma unroll
  for (int q = 0; q < 16; q++) W[q] = ((const float4*)(emb_W + lane * 64))[q];
  b = emb_b[lane];
#pragma unroll 1
  for (int t = 0; t < 16; t += 4) {
    int r = w * 16 + t;
    float a0 = b, a1 = b, a2 = b, a3 = b;
#pragma unroll
    for (int q = 0; q < 16; q++) {
      float4 v0 = *(const float4*)(sx + (r + 0) * 64 + q * 4);
      float4 v1 = *(const float4*)(sx + (r + 1) * 64 + q * 4);
      float4 v2 = *(const float4*)(sx + (r + 2) * 64 + q * 4);
      float4 v3 = *(const float4*)(sx + (r + 3) * 64 + q * 4);
      FMA4(a0, v0, W[q]);
      FMA4(a1, v1, W[q]);
      FMA4(a2, v2, W[q]);
      FMA4(a3, v3, W[q]);
    }
    sh[(r + 0) * 64 + lane] = a0;
    sh[(r + 1) * 64 + lane] = a1;
    sh[(r + 2) * 64 + lane] = a2;
    sh[(r + 3) * 64 + lane] = a3;
    int n = n0 + r;
    if (n + 0 < rows) h[(size_t)(n + 0) * 64 + lane] = a0;
    if (n + 1 < rows) h[(size_t)(n + 1) * 64 + lane] = a1;
    if (n + 2 < rows) h[(size_t)(n + 2) * 64 + lane] = a2;
    if (n + 3 < rows) h[(size_t)(n + 3) * 64 + lane] = a3;
  }
  // Wave reads back only its own 16 rows -> no barrier needed.

  // ---- Phase B: xl = h @ Wl0.T + bl0 ----
#pragma unroll
  for (int q = 0; q < 16; q++) W[q] = ((const float4*)(Wl0 + lane * 64))[q];
  b = bl0[lane];
#pragma unroll 1
  for (int t = 0; t < 16; t += 4) {
    int r = w * 16 + t;
    float a0 = b, a1 = b, a2 = b, a3 = b;
#pragma unroll
    for (int q = 0; q < 16; q++) {
      float4 v0 = *(const float4*)(sh + (r + 0) * 64 + q * 4);
      float4 v1 = *(const float4*)(sh + (r + 1) * 64 + q * 4);
      float4 v2 = *(const float4*)(sh + (r + 2) * 64 + q * 4);
      float4 v3 = *(const float4*)(sh + (r + 3) * 64 + q * 4);
      FMA4(a0, v0, W[q]);
      FMA4(a1, v1, W[q]);
      FMA4(a2, v2, W[q]);
      FMA4(a3, v3, W[q]);
    }
    int n = n0 + r;
    if (n + 0 < rows) xl[(size_t)(n + 0) * 64 + lane] = (_Float16)a0;
    if (n + 1 < rows) xl[(size_t)(n + 1) * 64 + lane] = (_Float16)a1;
    if (n + 2 < rows) xl[(size_t)(n + 2) * 64 + lane] = (_Float16)a2;
    if (n + 3 < rows) xl[(size_t)(n + 3) * 64 + lane] = (_Float16)a3;
  }

  // ---- Phase C: xr = h @ Wr0.T + br0 ----
#pragma unroll
  for (int q = 0; q < 16; q++) W[q] = ((const float4*)(Wr0 + lane * 64))[q];
  b = br0[lane];
#pragma unroll 1
  for (int t = 0; t < 16; t += 4) {
    int r = w * 16 + t;
    float a0 = b, a1 = b, a2 = b, a3 = b;
#pragma unroll
    for (int q = 0; q < 16; q++) {
      float4 v0 = *(const float4*)(sh + (r + 0) * 64 + q * 4);
      float4 v1 = *(const float4*)(sh + (r + 1) * 64 + q * 4);
      float4 v2 = *(const float4*)(sh + (r + 2) * 64 + q * 4);
      float4 v3 = *(const float4*)(sh + (r + 3) * 64 + q * 4);
      FMA4(a0, v0, W[q]);
      FMA4(a1, v1, W[q]);
      FMA4(a2, v2, W[q]);
      FMA4(a3, v3, W[q]);
    }
    int n = n0 + r;
    if (n + 0 < rows) xr[(size_t)(n + 0) * 64 + lane] = (_Float16)a0;
    if (n + 1 < rows) xr[(size_t)(n + 1) * 64 + lane] = (_Float16)a1;
    if (n + 2 < rows) xr[(size_t)(n + 2) * 64 + lane] = (_Float16)a2;
    if (n + 3 < rows) xr[(size_t)(n + 3) * 64 + lane] = (_Float16)a3;
  }
}

// ---------------------------------------------------------------------------
// xl/xr for layers 1,2: tile-staged h + two phased passes, hand-inlined.
// ---------------------------------------------------------------------------
__global__ __launch_bounds__(256, 3) void linx2_kernel(
    const float* __restrict__ in, const float* __restrict__ Wl,
    const float* __restrict__ bl, const float* __restrict__ Wr,
    const float* __restrict__ br, _Float16* __restrict__ xl,
    _Float16* __restrict__ xr, int rows) {
  __shared__ float sx[4096];
  int lane = threadIdx.x & 63;
  int w = threadIdx.x >> 6;
  int n0 = blockIdx.x * 64;

  {
    int gmax = rows * 64 - 4;
#pragma unroll
    for (int i = 0; i < 4; i++) {
      int off = w * 1024 + i * 256 + lane * 4;
      int g = min(n0 * 64 + off, gmax);
      *(float4*)(sx + off) = *(const float4*)(in + g);
    }
  }
  __syncthreads();

  float4 W[16];
  float b;

  // ---- xl ----
#pragma unroll
  for (int q = 0; q < 16; q++) W[q] = ((const float4*)(Wl + lane * 64))[q];
  b = bl[lane];
#pragma unroll 1
  for (int t = 0; t < 16; t += 4) {
    int r = w * 16 + t;
    float a0 = b, a1 = b, a2 = b, a3 = b;
#pragma unroll
    for (int q = 0; q < 16; q++) {
      float4 v0 = *(const float4*)(sx + (r + 0) * 64 + q * 4);
      float4 v1 = *(const float4*)(sx + (r + 1) * 64 + q * 4);
      float4 v2 = *(const float4*)(sx + (r + 2) * 64 + q * 4);
      float4 v3 = *(const float4*)(sx + (r + 3) * 64 + q * 4);
      FMA4(a0, v0, W[q]);
      FMA4(a1, v1, W[q]);
      FMA4(a2, v2, W[q]);
      FMA4(a3, v3, W[q]);
    }
    int n = n0 + r;
    if (n + 0 < rows) xl[(size_t)(n + 0) * 64 + lane] = (_Float16)a0;
    if (n + 1 < rows) xl[(size_t)(n + 1) * 64 + lane] = (_Float16)a1;
    if (n + 2 < rows) xl[(size_t)(n + 2) * 64 + lane] = (_Float16)a2;
    if (n + 3 < rows) xl[(size_t)(n + 3) * 64 + lane] = (_Float16)a3;
  }

  // ---- xr ----
#pragma unroll
  for (int q = 0; q < 16; q++) W[q] = ((const float4*)(Wr + lane * 64))[q];
  b = br[lane];
#pragma unroll 1
  for (int t = 0; t < 16; t += 4) {
    int r = w * 16 + t;
    float a0 = b, a1 = b, a2 = b, a3 = b;
#pragma unroll
    for (int q = 0; q < 16; q++) {
      float4 v0 = *(const float4*)(sx + (r + 0) * 64 + q * 4);
      float4 v1 = *(const float4*)(sx + (r + 1) * 64 + q * 4);
      float4 v2 = *(const float4*)(sx + (r + 2) * 64 + q * 4);
      float4 v3 = *(const float4*)(sx + (r + 3) * 64 + q * 4);
      FMA4(a0, v0, W[q]);
      FMA4(a1, v1, W[q]);
      FMA4(a2, v2, W[q]);
      FMA4(a3, v3, W[q]);
    }
    int n = n0 + r;
    if (n + 0 < rows) xr[(size_t)(n + 0) * 64 + lane] = (_Float16)a0;
    if (n + 1 < rows) xr[(size_t)(n + 1) * 64 + lane] = (_Float16)a1;
    if (n + 2 < rows) xr[(size_t)(n + 2) * 64 + lane] = (_Float16)a2;
    if (n + 3 < rows) xr[(size_t)(n + 3) * 64 + lane] = (_Float16)a3;
  }
}

// ---------------------------------------------------------------------------
// Fused GATv2 layer (round-8 proven structure): one wave per node; full-16 ->
// full-8 -> padded-8 chunks; wave-uniform scalar index/attr loads; 16
// independent fp16 xl gathers; ea via 8 v_dot2_f32_f16; DPP reduction;
// online-max softmax. Epilogue = folded conv_bias+BN, exact GELU, residual.
// ---------------------------------------------------------------------------
template <bool CONTIG>
__global__ __launch_bounds__(256) void gat_fused_kernel(
    const int* __restrict__ csr_src, const int* __restrict__ csr_eid,
    const int* __restrict__ row_ptr, const unsigned* __restrict__ attr_u,
    const float* __restrict__ edge_attr, const _Float16* __restrict__ xl,
    const _Float16* __restrict__ xr, const float* __restrict__ We,
    const float* __restrict__ att, const float* __restrict__ conv_bias,
    const float* __restrict__ gamma, const float* __restrict__ beta,
    const float* __restrict__ mean, const float* __restrict__ var,
    float* __restrict__ h, int N_) {
  int d = (blockIdx.x * 256 + threadIdx.x) >> 6;
  if (d >= N_) return;
  int j = threadIdx.x & 63;
  half2v Wek2[8];
  float Wekf[16];
  if constexpr (CONTIG) {
#pragma unroll
    for (int q = 0; q < 8; q++) {
      Wek2[q][0] = (_Float16)We[j * 16 + 2 * q];
      Wek2[q][1] = (_Float16)We[j * 16 + 2 * q + 1];
    }
  } else {
#pragma unroll
    for (int k = 0; k < 16; k++) Wekf[k] = We[j * 16 + k];
  }
  float att_j = att[j];
  float sc = rsqrtf(var[j] + BN_EPS) * gamma[j];
  float sh = (conv_bias[j] - mean[j]) * sc + beta[j];

  int beg = __builtin_amdgcn_readfirstlane(row_ptr[d]);
  int end = __builtin_amdgcn_readfirstlane(row_ptr[d + 1]);
  float xrj = (float)xr[(size_t)d * 64 + j];
  float m = -INFINITY, l = 0.f, acc = 0.f;

  auto chunk = [&](int base, auto C_, auto PAD_) {
    constexpr int C = decltype(C_)::v;
    constexpr bool PAD = decltype(PAD_)::v;
    int si[C];
#pragma unroll
    for (int t = 0; t < C; t++) {
      int idx = PAD ? min(base + t, end - 1) : (base + t);
      si[t] = csr_src[idx];
    }
    float xlv[C];
#pragma unroll
    for (int t = 0; t < C; t++)
      xlv[t] = (float)xl[(size_t)si[t] * 64 + j];
    float v[C];
#pragma unroll
    for (int t = 0; t < C; t++) {
      int idx = PAD ? min(base + t, end - 1) : (base + t);
      float ea;
      if constexpr (CONTIG) {
        const uint4* ap = (const uint4*)(attr_u + (size_t)idx * 8);
        uint4 ua = ap[0], ub = ap[1];  // uniform -> s_load_dwordx4
        ea = 0.f;
        ea = FDOT2(u2h(ua.x), Wek2[0], ea);
        ea = FDOT2(u2h(ua.y), Wek2[1], ea);
        ea = FDOT2(u2h(ua.z), Wek2[2], ea);
        ea = FDOT2(u2h(ua.w), Wek2[3], ea);
        ea = FDOT2(u2h(ub.x), Wek2[4], ea);
        ea = FDOT2(u2h(ub.y), Wek2[5], ea);
        ea = FDOT2(u2h(ub.z), Wek2[6], ea);
        ea = FDOT2(u2h(ub.w), Wek2[7], ea);
      } else {
        const float4* ap =
            (const float4*)(edge_attr + (size_t)csr_eid[idx] * 16);
        float4 a0 = ap[0], a1 = ap[1], a2 = ap[2], a3 = ap[3];
        ea = a0.x * Wekf[0]  + a0.y * Wekf[1]  + a0.z * Wekf[2]  + a0.w * Wekf[3]
           + a1.x * Wekf[4]  + a1.y * Wekf[5]  + a1.z * Wekf[6]  + a1.w * Wekf[7]
           + a2.x * Wekf[8]  + a2.y * Wekf[9]  + a2.z * Wekf[10] + a2.w * Wekf[11]
           + a3.x * Wekf[12] + a3.y * Wekf[13] + a3.z * Wekf[14] + a3.w * Wekf[15];
      }
      float z = xlv[t] + xrj + ea;
      z = fmaxf(z, NEG_SLOPE * z);  // leaky_relu
      float p = wave_sum64(z * att_j);
      v[t] = (!PAD || (base + t < end)) ? p : -INFINITY;
    }
    float mc = v[0];
#pragma unroll
    for (int t = 1; t < C; t++) mc = fmaxf(mc, v[t]);
    float newm = fmaxf(m, mc);
    float s = __expf(m - newm);  // first chunk: exp(-inf)=0
    l *= s;
    acc *= s;
#pragma unroll
    for (int t = 0; t < C; t++) {
      float w = __expf(v[t] - newm);  // padded slots: exp(-inf)=0
      l += w;
      acc += w * xlv[t];
    }
    m = newm;
  };

  int base = beg;
  for (; base + 16 <= end; base += 16) chunk(base, IC<16>{}, BC<false>{});
  if (base + 8 <= end) {
    chunk(base, IC<8>{}, BC<false>{});
    base += 8;
  }
  if (base < end) chunk(base, IC<8>{}, BC<true>{});

  float val = acc / (l + 1e-16f) * sc + sh;  // conv_bias+BN folded
  float g = 0.5f * val * (1.f + erff(val * 0.70710678118654752f));
  h[(size_t)d * 64 + j] += g;
}

// ---------------------------------------------------------------------------
// Final: out128 = h @ lin_W.T + lin_b, pooled per graph (batch sorted),
// mean fused at flush. Tile-staged h; wave w handles rows w*16..w*16+15,
// lane holds outputs (lane, lane+64); one broadcast ds_read feeds both dots.
// All dots hand-inlined.
// ---------------------------------------------------------------------------
__global__ __launch_bounds__(256, 2) void lin_pool_kernel(
    const float* __restrict__ h, const float* __restrict__ lin_W,
    const float* __restrict__ lin_b, const int* __restrict__ batch,
    const float* __restrict__ counts, float* __restrict__ pooled, int rows) {
  __shared__ float shh[4096];
  int lane = threadIdx.x & 63;
  int w = threadIdx.x >> 6;
  int n0 = blockIdx.x * 64;

  {
    int gmax = rows * 64 - 4;
#pragma unroll
    for (int i = 0; i < 4; i++) {
      int off = w * 1024 + i * 256 + lane * 4;
      int g = min(n0 * 64 + off, gmax);
      *(float4*)(shh + off) = *(const float4*)(h + g);
    }
  }
  __syncthreads();

  float4 W0[16], W1[16];
#pragma unroll
  for (int q = 0; q < 16; q++) W0[q] = ((const float4*)(lin_W + lane * 64))[q];
#pragma unroll
  for (int q = 0; q < 16; q++)
    W1[q] = ((const float4*)(lin_W + (lane + 64) * 64))[q];
  float b0 = lin_b[lane], b1 = lin_b[lane + 64];

  int curg = -1;
  float acc0 = 0.f, acc1 = 0.f;
  int lim = min(16, rows - n0 - w * 16);
#pragma unroll 1
  for (int t = 0; t < lim; t++) {
    int r = w * 16 + t;
    float d0 = b0, d1 = b1;
#pragma unroll
    for (int q = 0; q < 16; q++) {
      float4 v = *(const float4*)(shh + r * 64 + q * 4);
      FMA4(d0, v, W0[q]);
      FMA4(d1, v, W1[q]);
    }
    int g = batch[n0 + r];
    if (g != curg) {
      if (curg >= 0) {
        float inv = 1.f / fmaxf(counts[curg], 1.f);
        atomicAdd(&pooled[curg * 128 + lane], acc0 * inv);
        atomicAdd(&pooled[curg * 128 + 64 + lane], acc1 * inv);
      }
      curg = g;
      acc0 = 0.f;
      acc1 = 0.f;
    }
    acc0 += d0;
    acc1 += d1;
  }
  if (curg >= 0) {
    float inv = 1.f / fmaxf(counts[curg], 1.f);
    atomicAdd(&pooled[curg * 128 + lane], acc0 * inv);
    atomicAdd(&pooled[curg * 128 + 64 + lane], acc1 * inv);
  }
}

extern "C" void kernel_launch(void* const* d_in, const int* in_sizes, int n_in,
                              void* d_out, int out_size, void* d_ws, size_t ws_size,
                              hipStream_t stream) {
  const float* x         = (const float*)d_in[0];
  const int*   edge_index= (const int*)  d_in[1];
  const float* edge_attr = (const float*)d_in[2];
  const int*   batch     = (const int*)  d_in[3];
  const float* emb_W     = (const float*)d_in[4];
  const float* emb_b     = (const float*)d_in[5];
  const float* Wl        = (const float*)d_in[6];
  const float* bl        = (const float*)d_in[7];
  const float* Wr        = (const float*)d_in[8];
  const float* br        = (const float*)d_in[9];
  const float* We        = (const float*)d_in[10];
  const float* att       = (const float*)d_in[11];
  const float* conv_bias = (const float*)d_in[12];
  const float* bn_gamma  = (const float*)d_in[13];
  const float* bn_beta   = (const float*)d_in[14];
  const float* bn_mean   = (const float*)d_in[15];
  const float* bn_var    = (const float*)d_in[16];
  const float* lin_W     = (const float*)d_in[17];
  const float* lin_b     = (const float*)d_in[18];

  const int N_ = in_sizes[0] / 64;
  const int E_ = in_sizes[1] / 2;
  const int G_ = out_size / 128;
  const int* src = edge_index;
  const int* dst = edge_index + E_;

  const int Npad = (N_ + 3) & ~3;
  const int Epad = (E_ + 19) & ~3;
  const int nseg = (N_ + 255) / 256;

  // Workspace layout (floats). xl/xr are fp16 (N*32 float-slots each).
  float* ws      = (float*)d_ws;
  float* h       = ws;                                 // N*64
  _Float16* xl   = (_Float16*)(h + (size_t)N_ * 64);   // N*64 halfs
  _Float16* xr   = xl + (size_t)N_ * 64;               // N*64 halfs
  int*   csr_src = (int*)(xr + (size_t)N_ * 64);       // Epad
  int*   csr_eid = csr_src + Epad;                     // Epad
  int*   row_ptr = csr_eid + Epad;                     // Npad+4
  int*   cursor  = row_ptr + (Npad + 4);               // Npad
  int*   deg     = cursor + Npad;                      // Npad
  float* counts  = (float*)(deg + Npad);               // G
  int*   segTot  = (int*)(counts + G_);                // nseg+8
  uintptr_t abp  = (uintptr_t)(segTot + nseg + 8);
  abp = (abp + 15) & ~(uintptr_t)15;
  unsigned* attr_u = (unsigned*)abp;                   // E*8 uints (optional)

  size_t base_bytes = (abp - (uintptr_t)d_ws);
  bool contig = ws_size >= base_bytes + (size_t)E_ * 32 + 64;

  const int hgrid = (max(E_, N_) + 255) / 256;
  const int ngrid = (N_ + 255) / 256;

  // --- CSR build + graph counts (once per call, reused by all 3 layers) ---
  hipMemsetAsync(deg, 0, ((size_t)Npad + G_) * 4, stream);  // deg + counts
  hist_kernel<<<hgrid, 256, 0, stream>>>(dst, batch, deg, counts, E_, N_);
  scanA_kernel<<<min(nseg, 1024), 256, 0, stream>>>(deg, row_ptr, segTot, N_,
                                                    nseg);
  scanB_kernel<<<1, 256, 0, stream>>>(segTot, nseg);
  scanC_kernel<<<ngrid, 256, 0, stream>>>(row_ptr, segTot, cursor, N_, E_);
  scatter_kernel<<<(E_ + 255) / 256, 256, 0, stream>>>(
      src, dst, (const float4*)edge_attr, cursor, csr_src, csr_eid,
      contig ? attr_u : (unsigned*)nullptr, E_);

  // h = emb(x); xl/xr for layer 0 (tile-staged)
  const int tgrid = (N_ + 63) / 64;  // one 64-node tile per block
  emb_lin0_kernel<<<tgrid, 256, 0, stream>>>(x, emb_W, emb_b, Wl, bl, Wr, br,
                                             h, xl, xr, N_);

  const int gatBlocks = (N_ + 3) / 4;  // one wave per node
  for (int l = 0; l < 3; l++) {
    if (l > 0) {
      linx2_kernel<<<tgrid, 256, 0, stream>>>(
          h, Wl + (size_t)l * 4096, bl + l * 64, Wr + (size_t)l * 4096,
          br + l * 64, xl, xr, N_);
    }
    if (contig) {
      gat_fused_kernel<true><<<gatBlocks, 256, 0, stream>>>(
          csr_src, csr_eid, row_ptr, attr_u, edge_attr, xl, xr,
          We + (size_t)l * 1024, att + l * 64, conv_bias + l * 64,
          bn_gamma + l * 64, bn_beta + l * 64, bn_mean + l * 64,
          bn_var + l * 64, h, N_);
    } else {
      gat_fused_kernel<false><<<gatBlocks, 256, 0, stream>>>(
          csr_src, csr_eid, row_ptr, attr_u, edge_attr, xl, xr,
          We + (size_t)l * 1024, att + l * 64, conv_bias + l * 64,
          bn_gamma + l * 64, bn_beta + l * 64, bn_mean + l * 64,
          bn_var + l * 64, h, N_);
    }
  }

  hipMemsetAsync(d_out, 0, (size_t)G_ * 128 * 4, stream);
  lin_pool_kernel<<<(N_ + 63) / 64, 256, 0, stream>>>(
      h, lin_W, lin_b, batch, counts, (float*)d_out, N_);
}

// Round 4
// 621.841 us; speedup vs baseline: 2.6457x; 2.0447x over previous
//
#include <hip/hip_runtime.h>
#include <math.h>

#define NEG_SLOPE 0.2f
#define BN_EPS 1e-5f

template <int N> struct IC { static constexpr int v = N; };
template <bool B> struct BC { static constexpr bool v = B; };

typedef _Float16 half2v __attribute__((ext_vector_type(2)));

__device__ __forceinline__ half2v u2h(unsigned u) {
  union { unsigned u; half2v h; } c;
  c.u = u;
  return c.h;
}
__device__ __forceinline__ unsigned pkh(float lo, float hi) {
  union { half2v h; unsigned u; } c;
  c.h[0] = (_Float16)lo;
  c.h[1] = (_Float16)hi;
  return c.u;
}

#if defined(__has_builtin)
#if __has_builtin(__builtin_amdgcn_fdot2)
#define FDOT2(a, b, c) __builtin_amdgcn_fdot2((a), (b), (c), false)
#endif
#endif
#ifndef FDOT2
__device__ __forceinline__ float fdot2_sw(half2v a, half2v b, float c) {
  return c + (float)a[0] * (float)b[0] + (float)a[1] * (float)b[1];
}
#define FDOT2(a, b, c) fdot2_sw((a), (b), (c))
#endif

// FMA of one float4 pair into scalar accumulator (expanded inline at use).
#define FMA4(acc, v, wq) \
  acc += (v).x * (wq).x + (v).y * (wq).y + (v).z * (wq).z + (v).w * (wq).w

// One 64-dot row-pass against register-resident W[16] (float4).
// sched_barrier(0) fences the scheduler: max 16 ds_read_b128 in flight
// (64 VGPRs) -> W stays register-resident, no scratch spill.
#define DOT_ROW(buf, r, bias, OUT)                                     \
  {                                                                    \
    __builtin_amdgcn_sched_barrier(0);                                 \
    float a0 = 0.f, a1 = 0.f, a2 = 0.f, a3 = 0.f;                      \
    _Pragma("unroll") for (int q = 0; q < 4; q++) {                    \
      float4 v0 = *(const float4*)((buf) + (r) * 64 + q * 16 + 0);     \
      float4 v1 = *(const float4*)((buf) + (r) * 64 + q * 16 + 4);     \
      float4 v2 = *(const float4*)((buf) + (r) * 64 + q * 16 + 8);     \
      float4 v3 = *(const float4*)((buf) + (r) * 64 + q * 16 + 12);    \
      FMA4(a0, v0, W[q * 4 + 0]);                                      \
      FMA4(a1, v1, W[q * 4 + 1]);                                      \
      FMA4(a2, v2, W[q * 4 + 2]);                                      \
      FMA4(a3, v3, W[q * 4 + 3]);                                      \
    }                                                                  \
    OUT = (bias) + ((a0 + a1) + (a2 + a3));                            \
  }

// ---------------------------------------------------------------------------
// VALU-only 64-lane sum: 4 DPP row-rotate adds + 2 cross-row shuffles.
// ---------------------------------------------------------------------------
__device__ __forceinline__ float wave_sum64(float v) {
  int x;
  x = __builtin_amdgcn_update_dpp(0, __float_as_int(v), 0x121, 0xF, 0xF, true);
  v += __int_as_float(x);  // row_ror:1
  x = __builtin_amdgcn_update_dpp(0, __float_as_int(v), 0x122, 0xF, 0xF, true);
  v += __int_as_float(x);  // row_ror:2
  x = __builtin_amdgcn_update_dpp(0, __float_as_int(v), 0x124, 0xF, 0xF, true);
  v += __int_as_float(x);  // row_ror:4
  x = __builtin_amdgcn_update_dpp(0, __float_as_int(v), 0x128, 0xF, 0xF, true);
  v += __int_as_float(x);  // row_ror:8
  v += __shfl_xor(v, 16, 64);
  v += __shfl_xor(v, 32, 64);
  return v;
}

// ---------------------------------------------------------------------------
// hist + graph-counts merged.
// ---------------------------------------------------------------------------
__global__ __launch_bounds__(256) void hist_kernel(
    const int* __restrict__ dst, const int* __restrict__ batch,
    int* __restrict__ deg, float* __restrict__ counts, int E_, int N_) {
  int i = blockIdx.x * 256 + threadIdx.x;
  if (i < E_) atomicAdd(&deg[dst[i]], 1);
  if (i < N_) atomicAdd(&counts[batch[i]], 1.0f);
}

// ---------------------------------------------------------------------------
// Multi-block scan: A) per-256-segment local prefix + totals, B) one block
// scans totals, C) add offsets -> row_ptr/cursor.
// ---------------------------------------------------------------------------
__global__ __launch_bounds__(256) void scanA_kernel(
    const int* __restrict__ deg, int* __restrict__ row_ptr,
    int* __restrict__ segTot, int N_, int nseg) {
  __shared__ int sb[256];
  int t = threadIdx.x;
  for (int s = blockIdx.x; s < nseg; s += gridDim.x) {
    int i = s * 256 + t;
    int v = (i < N_) ? deg[i] : 0;
    sb[t] = v;
    __syncthreads();
    for (int off = 1; off < 256; off <<= 1) {
      int a = (t >= off) ? sb[t - off] : 0;
      __syncthreads();
      sb[t] += a;
      __syncthreads();
    }
    int incl = sb[t];
    if (i < N_) row_ptr[i] = incl - v;
    if (t == 255) segTot[s] = incl;
    __syncthreads();
  }
}

__global__ __launch_bounds__(256) void scanB_kernel(int* __restrict__ segTot,
                                                    int nseg) {
  __shared__ int sb[256];
  __shared__ int baseSh;
  int t = threadIdx.x;
  if (t == 0) baseSh = 0;
  __syncthreads();
  for (int c0 = 0; c0 < nseg; c0 += 256) {
    int s = c0 + t;
    int v = (s < nseg) ? segTot[s] : 0;
    sb[t] = v;
    __syncthreads();
    for (int off = 1; off < 256; off <<= 1) {
      int a = (t >= off) ? sb[t - off] : 0;
      __syncthreads();
      sb[t] += a;
      __syncthreads();
    }
    int incl = sb[t];
    int base = baseSh;
    if (s < nseg) segTot[s] = base + incl - v;
    __syncthreads();
    if (t == 255) baseSh = base + incl;
    __syncthreads();
  }
}

__global__ __launch_bounds__(256) void scanC_kernel(
    int* __restrict__ row_ptr, const int* __restrict__ segTot,
    int* __restrict__ cursor, int N_, int E_) {
  int tid = blockIdx.x * 256 + threadIdx.x;
  int nt = gridDim.x * 256;
  for (int i = tid; i < N_; i += nt) {
    int rp = row_ptr[i] + segTot[i >> 8];
    row_ptr[i] = rp;
    cursor[i] = rp;
  }
  if (tid == 0) row_ptr[N_] = E_;
}

// ---------------------------------------------------------------------------
// Scatter: src into CSR slot + attr permuted & converted to fp16 (32B/edge).
// Fallback (no ws room): write eid only, gat reads fp32 edge_attr.
// ---------------------------------------------------------------------------
__global__ __launch_bounds__(256) void scatter_kernel(
    const int* __restrict__ src, const int* __restrict__ dst,
    const float4* __restrict__ edge_attr4, int* __restrict__ cursor,
    int* __restrict__ csr_src, int* __restrict__ csr_eid,
    unsigned* __restrict__ attr_u, int E_) {
  int e = blockIdx.x * 256 + threadIdx.x;
  if (e >= E_) return;
  int pos = atomicAdd(&cursor[dst[e]], 1);
  csr_src[pos] = src[e];
  if (attr_u) {
    float4 a0 = edge_attr4[e * 4 + 0];
    float4 a1 = edge_attr4[e * 4 + 1];
    float4 a2 = edge_attr4[e * 4 + 2];
    float4 a3 = edge_attr4[e * 4 + 3];
    uint4 u0, u1;
    u0.x = pkh(a0.x, a0.y);
    u0.y = pkh(a0.z, a0.w);
    u0.z = pkh(a1.x, a1.y);
    u0.w = pkh(a1.z, a1.w);
    u1.x = pkh(a2.x, a2.y);
    u1.y = pkh(a2.z, a2.w);
    u1.z = pkh(a3.x, a3.y);
    u1.w = pkh(a3.z, a3.w);
    uint4* d4 = (uint4*)(attr_u + (size_t)pos * 8);
    d4[0] = u0;
    d4[1] = u1;
  } else {
    csr_eid[pos] = e;
  }
}

// ---------------------------------------------------------------------------
// Fused emb + layer-0 xl/xr, tile-staged, spill-proof:
//   - each wave stages its OWN 16 rows into LDS (coalesced float4) and only
//     ever reads those rows back -> LDS is per-wave scratch, NO barriers.
//   - one row per unroll-1 iteration, sched_barrier(0) fence per row ->
//     max 16 ds_read_b128 in flight; W[16] stays in VGPRs (no scratch).
//   - phased (one W at a time): Phase A h=emb(x) (also -> sh slab),
//     Phase B xl, Phase C xr from sh.
// ---------------------------------------------------------------------------
__global__ __launch_bounds__(256, 3) void emb_lin0_kernel(
    const float* __restrict__ x, const float* __restrict__ emb_W,
    const float* __restrict__ emb_b, const float* __restrict__ Wl0,
    const float* __restrict__ bl0, const float* __restrict__ Wr0,
    const float* __restrict__ br0, float* __restrict__ h,
    _Float16* __restrict__ xl, _Float16* __restrict__ xr, int rows) {
  __shared__ float sx[4096];
  __shared__ float sh[4096];
  int lane = threadIdx.x & 63;
  int w = threadIdx.x >> 6;
  int n0 = blockIdx.x * 64;

  {  // stage: wave w loads exactly rows [w*16, w*16+16) -> its own slab
    int gmax = rows * 64 - 4;
#pragma unroll
    for (int i = 0; i < 4; i++) {
      int off = w * 1024 + i * 256 + lane * 4;
      int g = min(n0 * 64 + off, gmax);
      *(float4*)(sx + off) = *(const float4*)(x + g);
    }
  }

  float4 W[16];
  float b;

  // ---- Phase A: h = x @ emb_W.T + emb_b ----
#pragma unroll
  for (int q = 0; q < 16; q++) W[q] = ((const float4*)(emb_W + lane * 64))[q];
  b = emb_b[lane];
#pragma unroll 1
  for (int t = 0; t < 16; t++) {
    int r = w * 16 + t;
    float a;
    DOT_ROW(sx, r, b, a);
    sh[r * 64 + lane] = a;
    int n = n0 + r;
    if (n < rows) h[(size_t)n * 64 + lane] = a;
  }

  // ---- Phase B: xl = h @ Wl0.T + bl0 (reads own rows of sh) ----
#pragma unroll
  for (int q = 0; q < 16; q++) W[q] = ((const float4*)(Wl0 + lane * 64))[q];
  b = bl0[lane];
#pragma unroll 1
  for (int t = 0; t < 16; t++) {
    int r = w * 16 + t;
    float a;
    DOT_ROW(sh, r, b, a);
    int n = n0 + r;
    if (n < rows) xl[(size_t)n * 64 + lane] = (_Float16)a;
  }

  // ---- Phase C: xr = h @ Wr0.T + br0 ----
#pragma unroll
  for (int q = 0; q < 16; q++) W[q] = ((const float4*)(Wr0 + lane * 64))[q];
  b = br0[lane];
#pragma unroll 1
  for (int t = 0; t < 16; t++) {
    int r = w * 16 + t;
    float a;
    DOT_ROW(sh, r, b, a);
    int n = n0 + r;
    if (n < rows) xr[(size_t)n * 64 + lane] = (_Float16)a;
  }
}

// ---------------------------------------------------------------------------
// xl/xr for layers 1,2: same spill-proof structure, input h from global.
// ---------------------------------------------------------------------------
__global__ __launch_bounds__(256, 3) void linx2_kernel(
    const float* __restrict__ in, const float* __restrict__ Wl,
    const float* __restrict__ bl, const float* __restrict__ Wr,
    const float* __restrict__ br, _Float16* __restrict__ xl,
    _Float16* __restrict__ xr, int rows) {
  __shared__ float sx[4096];
  int lane = threadIdx.x & 63;
  int w = threadIdx.x >> 6;
  int n0 = blockIdx.x * 64;

  {
    int gmax = rows * 64 - 4;
#pragma unroll
    for (int i = 0; i < 4; i++) {
      int off = w * 1024 + i * 256 + lane * 4;
      int g = min(n0 * 64 + off, gmax);
      *(float4*)(sx + off) = *(const float4*)(in + g);
    }
  }

  float4 W[16];
  float b;

  // ---- xl ----
#pragma unroll
  for (int q = 0; q < 16; q++) W[q] = ((const float4*)(Wl + lane * 64))[q];
  b = bl[lane];
#pragma unroll 1
  for (int t = 0; t < 16; t++) {
    int r = w * 16 + t;
    float a;
    DOT_ROW(sx, r, b, a);
    int n = n0 + r;
    if (n < rows) xl[(size_t)n * 64 + lane] = (_Float16)a;
  }

  // ---- xr ----
#pragma unroll
  for (int q = 0; q < 16; q++) W[q] = ((const float4*)(Wr + lane * 64))[q];
  b = br[lane];
#pragma unroll 1
  for (int t = 0; t < 16; t++) {
    int r = w * 16 + t;
    float a;
    DOT_ROW(sx, r, b, a);
    int n = n0 + r;
    if (n < rows) xr[(size_t)n * 64 + lane] = (_Float16)a;
  }
}

// ---------------------------------------------------------------------------
// Fused GATv2 layer (round-8 proven structure): one wave per node; full-16 ->
// full-8 -> padded-8 chunks; wave-uniform scalar index/attr loads; 16
// independent fp16 xl gathers; ea via 8 v_dot2_f32_f16; DPP reduction;
// online-max softmax. Epilogue = folded conv_bias+BN, exact GELU, residual.
// ---------------------------------------------------------------------------
template <bool CONTIG>
__global__ __launch_bounds__(256) void gat_fused_kernel(
    const int* __restrict__ csr_src, const int* __restrict__ csr_eid,
    const int* __restrict__ row_ptr, const unsigned* __restrict__ attr_u,
    const float* __restrict__ edge_attr, const _Float16* __restrict__ xl,
    const _Float16* __restrict__ xr, const float* __restrict__ We,
    const float* __restrict__ att, const float* __restrict__ conv_bias,
    const float* __restrict__ gamma, const float* __restrict__ beta,
    const float* __restrict__ mean, const float* __restrict__ var,
    float* __restrict__ h, int N_) {
  int d = (blockIdx.x * 256 + threadIdx.x) >> 6;
  if (d >= N_) return;
  int j = threadIdx.x & 63;
  half2v Wek2[8];
  float Wekf[16];
  if constexpr (CONTIG) {
#pragma unroll
    for (int q = 0; q < 8; q++) {
      Wek2[q][0] = (_Float16)We[j * 16 + 2 * q];
      Wek2[q][1] = (_Float16)We[j * 16 + 2 * q + 1];
    }
  } else {
#pragma unroll
    for (int k = 0; k < 16; k++) Wekf[k] = We[j * 16 + k];
  }
  float att_j = att[j];
  float sc = rsqrtf(var[j] + BN_EPS) * gamma[j];
  float sh = (conv_bias[j] - mean[j]) * sc + beta[j];

  int beg = __builtin_amdgcn_readfirstlane(row_ptr[d]);
  int end = __builtin_amdgcn_readfirstlane(row_ptr[d + 1]);
  float xrj = (float)xr[(size_t)d * 64 + j];
  float m = -INFINITY, l = 0.f, acc = 0.f;

  auto chunk = [&](int base, auto C_, auto PAD_) {
    constexpr int C = decltype(C_)::v;
    constexpr bool PAD = decltype(PAD_)::v;
    int si[C];
#pragma unroll
    for (int t = 0; t < C; t++) {
      int idx = PAD ? min(base + t, end - 1) : (base + t);
      si[t] = csr_src[idx];
    }
    float xlv[C];
#pragma unroll
    for (int t = 0; t < C; t++)
      xlv[t] = (float)xl[(size_t)si[t] * 64 + j];
    float v[C];
#pragma unroll
    for (int t = 0; t < C; t++) {
      int idx = PAD ? min(base + t, end - 1) : (base + t);
      float ea;
      if constexpr (CONTIG) {
        const uint4* ap = (const uint4*)(attr_u + (size_t)idx * 8);
        uint4 ua = ap[0], ub = ap[1];  // uniform -> s_load_dwordx4
        ea = 0.f;
        ea = FDOT2(u2h(ua.x), Wek2[0], ea);
        ea = FDOT2(u2h(ua.y), Wek2[1], ea);
        ea = FDOT2(u2h(ua.z), Wek2[2], ea);
        ea = FDOT2(u2h(ua.w), Wek2[3], ea);
        ea = FDOT2(u2h(ub.x), Wek2[4], ea);
        ea = FDOT2(u2h(ub.y), Wek2[5], ea);
        ea = FDOT2(u2h(ub.z), Wek2[6], ea);
        ea = FDOT2(u2h(ub.w), Wek2[7], ea);
      } else {
        const float4* ap =
            (const float4*)(edge_attr + (size_t)csr_eid[idx] * 16);
        float4 a0 = ap[0], a1 = ap[1], a2 = ap[2], a3 = ap[3];
        ea = a0.x * Wekf[0]  + a0.y * Wekf[1]  + a0.z * Wekf[2]  + a0.w * Wekf[3]
           + a1.x * Wekf[4]  + a1.y * Wekf[5]  + a1.z * Wekf[6]  + a1.w * Wekf[7]
           + a2.x * Wekf[8]  + a2.y * Wekf[9]  + a2.z * Wekf[10] + a2.w * Wekf[11]
           + a3.x * Wekf[12] + a3.y * Wekf[13] + a3.z * Wekf[14] + a3.w * Wekf[15];
      }
      float z = xlv[t] + xrj + ea;
      z = fmaxf(z, NEG_SLOPE * z);  // leaky_relu
      float p = wave_sum64(z * att_j);
      v[t] = (!PAD || (base + t < end)) ? p : -INFINITY;
    }
    float mc = v[0];
#pragma unroll
    for (int t = 1; t < C; t++) mc = fmaxf(mc, v[t]);
    float newm = fmaxf(m, mc);
    float s = __expf(m - newm);  // first chunk: exp(-inf)=0
    l *= s;
    acc *= s;
#pragma unroll
    for (int t = 0; t < C; t++) {
      float w = __expf(v[t] - newm);  // padded slots: exp(-inf)=0
      l += w;
      acc += w * xlv[t];
    }
    m = newm;
  };

  int base = beg;
  for (; base + 16 <= end; base += 16) chunk(base, IC<16>{}, BC<false>{});
  if (base + 8 <= end) {
    chunk(base, IC<8>{}, BC<false>{});
    base += 8;
  }
  if (base < end) chunk(base, IC<8>{}, BC<true>{});

  float val = acc / (l + 1e-16f) * sc + sh;  // conv_bias+BN folded
  float g = 0.5f * val * (1.f + erff(val * 0.70710678118654752f));
  h[(size_t)d * 64 + j] += g;
}

// ---------------------------------------------------------------------------
// Final: out128 = h @ lin_W.T + lin_b, pooled per graph (batch sorted),
// mean fused at flush. Per-wave tile slab (own 16 rows, no barrier); lane
// holds outputs (lane, lane+64); sched_barrier per row fences hoisting.
// ---------------------------------------------------------------------------
__global__ __launch_bounds__(256, 2) void lin_pool_kernel(
    const float* __restrict__ h, const float* __restrict__ lin_W,
    const float* __restrict__ lin_b, const int* __restrict__ batch,
    const float* __restrict__ counts, float* __restrict__ pooled, int rows) {
  __shared__ float shh[4096];
  int lane = threadIdx.x & 63;
  int w = threadIdx.x >> 6;
  int n0 = blockIdx.x * 64;

  {
    int gmax = rows * 64 - 4;
#pragma unroll
    for (int i = 0; i < 4; i++) {
      int off = w * 1024 + i * 256 + lane * 4;
      int g = min(n0 * 64 + off, gmax);
      *(float4*)(shh + off) = *(const float4*)(h + g);
    }
  }

  float4 W0[16], W1[16];
#pragma unroll
  for (int q = 0; q < 16; q++) W0[q] = ((const float4*)(lin_W + lane * 64))[q];
#pragma unroll
  for (int q = 0; q < 16; q++)
    W1[q] = ((const float4*)(lin_W + (lane + 64) * 64))[q];
  float b0 = lin_b[lane], b1 = lin_b[lane + 64];

  int curg = -1;
  float acc0 = 0.f, acc1 = 0.f;
  int lim = min(16, rows - n0 - w * 16);
#pragma unroll 1
  for (int t = 0; t < lim; t++) {
    int r = w * 16 + t;
    __builtin_amdgcn_sched_barrier(0);
    float d0 = b0, d1 = b1;
#pragma unroll
    for (int q = 0; q < 16; q++) {
      float4 v = *(const float4*)(shh + r * 64 + q * 4);
      FMA4(d0, v, W0[q]);
      FMA4(d1, v, W1[q]);
    }
    int g = batch[n0 + r];
    if (g != curg) {
      if (curg >= 0) {
        float inv = 1.f / fmaxf(counts[curg], 1.f);
        atomicAdd(&pooled[curg * 128 + lane], acc0 * inv);
        atomicAdd(&pooled[curg * 128 + 64 + lane], acc1 * inv);
      }
      curg = g;
      acc0 = 0.f;
      acc1 = 0.f;
    }
    acc0 += d0;
    acc1 += d1;
  }
  if (curg >= 0) {
    float inv = 1.f / fmaxf(counts[curg], 1.f);
    atomicAdd(&pooled[curg * 128 + lane], acc0 * inv);
    atomicAdd(&pooled[curg * 128 + 64 + lane], acc1 * inv);
  }
}

extern "C" void kernel_launch(void* const* d_in, const int* in_sizes, int n_in,
                              void* d_out, int out_size, void* d_ws, size_t ws_size,
                              hipStream_t stream) {
  const float* x         = (const float*)d_in[0];
  const int*   edge_index= (const int*)  d_in[1];
  const float* edge_attr = (const float*)d_in[2];
  const int*   batch     = (const int*)  d_in[3];
  const float* emb_W     = (const float*)d_in[4];
  const float* emb_b     = (const float*)d_in[5];
  const float* Wl        = (const float*)d_in[6];
  const float* bl        = (const float*)d_in[7];
  const float* Wr        = (const float*)d_in[8];
  const float* br        = (const float*)d_in[9];
  const float* We        = (const float*)d_in[10];
  const float* att       = (const float*)d_in[11];
  const float* conv_bias = (const float*)d_in[12];
  const float* bn_gamma  = (const float*)d_in[13];
  const float* bn_beta   = (const float*)d_in[14];
  const float* bn_mean   = (const float*)d_in[15];
  const float* bn_var    = (const float*)d_in[16];
  const float* lin_W     = (const float*)d_in[17];
  const float* lin_b     = (const float*)d_in[18];

  const int N_ = in_sizes[0] / 64;
  const int E_ = in_sizes[1] / 2;
  const int G_ = out_size / 128;
  const int* src = edge_index;
  const int* dst = edge_index + E_;

  const int Npad = (N_ + 3) & ~3;
  const int Epad = (E_ + 19) & ~3;
  const int nseg = (N_ + 255) / 256;

  // Workspace layout (floats). xl/xr are fp16 (N*32 float-slots each).
  float* ws      = (float*)d_ws;
  float* h       = ws;                                 // N*64
  _Float16* xl   = (_Float16*)(h + (size_t)N_ * 64);   // N*64 halfs
  _Float16* xr   = xl + (size_t)N_ * 64;               // N*64 halfs
  int*   csr_src = (int*)(xr + (size_t)N_ * 64);       // Epad
  int*   csr_eid = csr_src + Epad;                     // Epad
  int*   row_ptr = csr_eid + Epad;                     // Npad+4
  int*   cursor  = row_ptr + (Npad + 4);               // Npad
  int*   deg     = cursor + Npad;                      // Npad
  float* counts  = (float*)(deg + Npad);               // G
  int*   segTot  = (int*)(counts + G_);                // nseg+8
  uintptr_t abp  = (uintptr_t)(segTot + nseg + 8);
  abp = (abp + 15) & ~(uintptr_t)15;
  unsigned* attr_u = (unsigned*)abp;                   // E*8 uints (optional)

  size_t base_bytes = (abp - (uintptr_t)d_ws);
  bool contig = ws_size >= base_bytes + (size_t)E_ * 32 + 64;

  const int hgrid = (max(E_, N_) + 255) / 256;
  const int ngrid = (N_ + 255) / 256;

  // --- CSR build + graph counts (once per call, reused by all 3 layers) ---
  hipMemsetAsync(deg, 0, ((size_t)Npad + G_) * 4, stream);  // deg + counts
  hist_kernel<<<hgrid, 256, 0, stream>>>(dst, batch, deg, counts, E_, N_);
  scanA_kernel<<<min(nseg, 1024), 256, 0, stream>>>(deg, row_ptr, segTot, N_,
                                                    nseg);
  scanB_kernel<<<1, 256, 0, stream>>>(segTot, nseg);
  scanC_kernel<<<ngrid, 256, 0, stream>>>(row_ptr, segTot, cursor, N_, E_);
  scatter_kernel<<<(E_ + 255) / 256, 256, 0, stream>>>(
      src, dst, (const float4*)edge_attr, cursor, csr_src, csr_eid,
      contig ? attr_u : (unsigned*)nullptr, E_);

  // h = emb(x); xl/xr for layer 0 (tile-staged)
  const int tgrid = (N_ + 63) / 64;  // one 64-node tile per block
  emb_lin0_kernel<<<tgrid, 256, 0, stream>>>(x, emb_W, emb_b, Wl, bl, Wr, br,
                                             h, xl, xr, N_);

  const int gatBlocks = (N_ + 3) / 4;  // one wave per node
  for (int l = 0; l < 3; l++) {
    if (l > 0) {
      linx2_kernel<<<tgrid, 256, 0, stream>>>(
          h, Wl + (size_t)l * 4096, bl + l * 64, Wr + (size_t)l * 4096,
          br + l * 64, xl, xr, N_);
    }
    if (contig) {
      gat_fused_kernel<true><<<gatBlocks, 256, 0, stream>>>(
          csr_src, csr_eid, row_ptr, attr_u, edge_attr, xl, xr,
          We + (size_t)l * 1024, att + l * 64, conv_bias + l * 64,
          bn_gamma + l * 64, bn_beta + l * 64, bn_mean + l * 64,
          bn_var + l * 64, h, N_);
    } else {
      gat_fused_kernel<false><<<gatBlocks, 256, 0, stream>>>(
          csr_src, csr_eid, row_ptr, attr_u, edge_attr, xl, xr,
          We + (size_t)l * 1024, att + l * 64, conv_bias + l * 64,
          bn_gamma + l * 64, bn_beta + l * 64, bn_mean + l * 64,
          bn_var + l * 64, h, N_);
    }
  }

  hipMemsetAsync(d_out, 0, (size_t)G_ * 128 * 4, stream);
  lin_pool_kernel<<<(N_ + 63) / 64, 256, 0, stream>>>(
      h, lin_W, lin_b, batch, counts, (float*)d_out, N_);
}